// Round 9
// baseline (473.735 us; speedup 1.0000x reference)
//
#include <hip/hip_runtime.h>
#include <hip/hip_fp16.h>

#define BATCH 4
#define NSEQ 2048
#define DMODEL 512
#define NHEAD 8
#define HDIM 64
#define LSEL 32
#define MAXL 64
#define QROWS 16
#define CSTRIDE 331   // cand row stride in u32 (5 levels x 66 + pad)

typedef __attribute__((ext_vector_type(8))) _Float16 f16x8;
typedef __attribute__((ext_vector_type(4))) float f32x4;
typedef unsigned long long ull;

__device__ inline ushort f2h(float x) { __half h = __float2half(x); return *reinterpret_cast<ushort*>(&h); }
__device__ inline float h16f(ushort u) { __half t; *reinterpret_cast<ushort*>(&t) = u; return __half2float(t); }
__device__ inline float sort2f(uint su) {
    ushort hb = (su & 0x8000u) ? (ushort)(su ^ 0x8000u) : (ushort)(su ^ 0xFFFFu);
    return h16f(hb);
}
// packed sortable map: per u16 half, neg -> ^0xFFFF, pos -> |0x8000
__device__ inline uint sm2(uint w) {
    uint s = (w >> 15) & 0x00010001u;
    uint m = s * 0x7FFFu;
    return w ^ (m | 0x80008000u);
}

// ---------------------------------------------------------------------------
// cvtA: fp32 -> fp16 copies of q,k,v
// ---------------------------------------------------------------------------
__global__ __launch_bounds__(256) void cvtA_kernel(
    const float* __restrict__ q, const float* __restrict__ k, const float* __restrict__ v,
    ushort* __restrict__ q16, ushort* __restrict__ k16, ushort* __restrict__ v16)
{
    const int z = blockIdx.y;
    const float* src = (z == 0) ? q : (z == 1) ? k : v;
    ushort* dst = (z == 0) ? q16 : (z == 1) ? k16 : v16;
    const size_t base = (size_t)blockIdx.x * 2048 + threadIdx.x * 4;
    float4 fa = *(const float4*)(src + base);
    float4 fb = *(const float4*)(src + base + 1024);
    ushort4 ha = {f2h(fa.x), f2h(fa.y), f2h(fa.z), f2h(fa.w)};
    ushort4 hb = {f2h(fb.x), f2h(fb.y), f2h(fb.z), f2h(fb.w)};
    *(ushort4*)(dst + base) = ha;
    *(ushort4*)(dst + base + 1024) = hb;
}

// ---------------------------------------------------------------------------
// cvtW: W[512][512] fp32 -> Wt[n][k] fp16 (transposed), 4 matrices
// ---------------------------------------------------------------------------
__global__ __launch_bounds__(256) void cvtW_kernel(
    const float* __restrict__ Wq, const float* __restrict__ Wk,
    const float* __restrict__ Wv, const float* __restrict__ Wfc,
    ushort* __restrict__ Wt)
{
    const int z = blockIdx.y;
    const float* W = (z == 0) ? Wq : (z == 1) ? Wk : (z == 2) ? Wv : Wfc;
    ushort* O = Wt + (size_t)z * DMODEL * DMODEL;
    const int gt = blockIdx.x * 256 + threadIdx.x;
    const int n = gt & 511;
    const int kc = (gt >> 9) * 16;
    uint pk[8];
#pragma unroll
    for (int i = 0; i < 8; ++i) {
        uint lo = f2h(W[(size_t)(kc + 2 * i) * DMODEL + n]);
        uint hi = f2h(W[(size_t)(kc + 2 * i + 1) * DMODEL + n]);
        pk[i] = lo | (hi << 16);
    }
    uint4 u0 = {pk[0], pk[1], pk[2], pk[3]};
    uint4 u1 = {pk[4], pk[5], pk[6], pk[7]};
    *(uint4*)(O + (size_t)n * DMODEL + kc) = u0;
    *(uint4*)(O + (size_t)n * DMODEL + kc + 8) = u1;
}

// ---------------------------------------------------------------------------
// hgemm: OUT[8192,512] = A16[8192,512] @ W (Wt stored [n][k] fp16).
// MODE 0: head-split fp16 out; z==0 (Q) pre-scaled by 0.125.
// MODE 1: fp32 row-major out.
// ---------------------------------------------------------------------------
template<int MODE>
__global__ __launch_bounds__(256, 2) void hgemm_kernel(
    const ushort* __restrict__ A0, const ushort* __restrict__ A1, const ushort* __restrict__ A2,
    const ushort* __restrict__ Wt,
    ushort* __restrict__ O0, ushort* __restrict__ O1, ushort* __restrict__ O2,
    float* __restrict__ Ofc)
{
    __shared__ ushort Ah[64][40];
    __shared__ ushort Bh[512][40];

    const int tid = threadIdx.x;
    const int wave = tid >> 6, lane = tid & 63;
    const int lr = lane & 15, lg = lane >> 4;
    const int bm = blockIdx.x * 64;
    const int z = blockIdx.y;

    const ushort* A16 = (MODE == 0) ? (z == 0 ? A0 : z == 1 ? A1 : A2) : A0;
    const ushort* Wz = Wt + (size_t)((MODE == 0) ? z : 3) * (DMODEL * DMODEL);

    f32x4 acc[4][8];
#pragma unroll
    for (int i = 0; i < 4; ++i)
#pragma unroll
        for (int j = 0; j < 8; ++j) acc[i][j] = (f32x4){0.f, 0.f, 0.f, 0.f};

    const int sar = tid >> 2, sak = (tid & 3) * 8;

    for (int k0 = 0; k0 < DMODEL; k0 += 32) {
        __syncthreads();
        *(uint4*)&Ah[sar][sak] = *(const uint4*)(A16 + (size_t)(bm + sar) * DMODEL + k0 + sak);
#pragma unroll
        for (int i = 0; i < 8; ++i) {
            int n = sar + 64 * i;
            *(uint4*)&Bh[n][sak] = *(const uint4*)(Wz + (size_t)n * DMODEL + k0 + sak);
        }
        __syncthreads();
        f16x8 af[4];
#pragma unroll
        for (int fr = 0; fr < 4; ++fr) af[fr] = *(const f16x8*)&Ah[fr * 16 + lr][lg * 8];
#pragma unroll
        for (int fc2 = 0; fc2 < 8; ++fc2) {
            f16x8 bf = *(const f16x8*)&Bh[wave * 128 + fc2 * 16 + lr][lg * 8];
#pragma unroll
            for (int fr = 0; fr < 4; ++fr)
                acc[fr][fc2] = __builtin_amdgcn_mfma_f32_16x16x32_f16(af[fr], bf, acc[fr][fc2], 0, 0, 0);
        }
    }

    if (MODE == 1) {
#pragma unroll
        for (int fr = 0; fr < 4; ++fr)
#pragma unroll
            for (int fc2 = 0; fc2 < 8; ++fc2)
#pragma unroll
                for (int r = 0; r < 4; ++r)
                    Ofc[(size_t)(bm + fr * 16 + lg * 4 + r) * DMODEL + wave * 128 + fc2 * 16 + lr] = acc[fr][fc2][r];
        return;
    }

    // MODE 0 epilogue: LDS transpose -> coalesced head-split fp16 stores
    const float osc = (z == 0) ? 0.125f : 1.0f;   // fold QK^T scale into Q
    ushort* O = (z == 0) ? O0 : (z == 1) ? O1 : O2;
    const int b = bm >> 11;
    const int nseq0 = bm & (NSEQ - 1);
    ushort* smw = (ushort*)&Bh[0][0] + wave * (64 * 72);
#pragma unroll
    for (int hp = 0; hp < 2; ++hp) {
        __syncthreads();
#pragma unroll
        for (int f4 = 0; f4 < 4; ++f4) {
            int fc2 = hp * 4 + f4;
            int nl = f4 * 16 + lr;
#pragma unroll
            for (int fr = 0; fr < 4; ++fr)
#pragma unroll
                for (int r = 0; r < 4; ++r)
                    smw[(fr * 16 + lg * 4 + r) * 72 + nl] = f2h(acc[fr][fc2][r] * osc);
        }
        __syncthreads();
        const int h = wave * 2 + hp;
        ushort* obase = O + ((size_t)(b * NHEAD + h) * NSEQ + nseq0) * HDIM;
#pragma unroll
        for (int i = 0; i < 8; ++i) {
            int m = i * 8 + (lane >> 3);
            int dc = (lane & 7) * 8;
            *(uint4*)(obase + (size_t)m * HDIM + dc) = *(const uint4*)(smw + m * 72 + dc);
        }
    }
}

// ---------------------------------------------------------------------------
// attention slow-path helpers (full-wave scans over a 2048-score row)
// ---------------------------------------------------------------------------
__device__ inline int wave_sum6(int c) {
    int tot = (int)__popcll(__ballot(c & 1));
    tot += (int)__popcll(__ballot(c & 2)) << 1;
    tot += (int)__popcll(__ballot(c & 4)) << 2;
    tot += (int)__popcll(__ballot(c & 8)) << 3;
    tot += (int)__popcll(__ballot(c & 16)) << 4;
    tot += (int)__popcll(__ballot(c & 32)) << 5;
    return tot;
}

__device__ uint full_thr(const ushort* Sr, int lane, uint lo0) {
    uint flo = lo0, fhi = 0xFFFFu;
#pragma unroll 1
    for (int it2 = 0; it2 < 16; ++it2) {
        uint mid = (flo + fhi + 1) >> 1, M = mid << 16;
        int cl = 0;
#pragma unroll
        for (int it = 0; it < 4; ++it) {
            uint4 r4 = *(const uint4*)(Sr + it * 512 + lane * 8);
            cl += ((r4.x << 16) >= M) + ((r4.x & 0xFFFF0000u) >= M);
            cl += ((r4.y << 16) >= M) + ((r4.y & 0xFFFF0000u) >= M);
            cl += ((r4.z << 16) >= M) + ((r4.z & 0xFFFF0000u) >= M);
            cl += ((r4.w << 16) >= M) + ((r4.w & 0xFFFF0000u) >= M);
        }
        bool ge = wave_sum6(cl) >= LSEL;
        flo = ge ? mid : flo;
        fhi = ge ? fhi : mid - 1;
    }
    return flo;
}

__device__ int recount(const ushort* Sr, int lane, uint th) {
    int cs = 0;
#pragma unroll
    for (int it = 0; it < 4; ++it) {
        uint4 r4 = *(const uint4*)(Sr + it * 512 + lane * 8);
        cs += ((r4.x << 16) >= th) + ((r4.x & 0xFFFF0000u) >= th);
        cs += ((r4.y << 16) >= th) + ((r4.y & 0xFFFF0000u) >= th);
        cs += ((r4.z << 16) >= th) + ((r4.z & 0xFFFF0000u) >= th);
        cs += ((r4.w << 16) >= th) + ((r4.w & 0xFFFF0000u) >= th);
    }
    return cs;
}

// full-row extraction (slow path): writes packed (w16<<16|idx)
__device__ float extract_big(const ushort* Sr, int lane, uint th, float Mv,
                             int pre, uint* selrow)
{
    const float L2E = 1.4426950408889634f;
    float wp = 0.f;
    int pos = pre;
#pragma unroll
    for (int it = 0; it < 4; ++it) {
        uint4 r4 = *(const uint4*)(Sr + it * 512 + lane * 8);
        uint ib = (uint)(it * 512 + lane * 8);
        uint wds[4] = {r4.x, r4.y, r4.z, r4.w};
#pragma unroll
        for (int c = 0; c < 4; ++c) {
            uint vL = wds[c] << 16, vH = wds[c] & 0xFFFF0000u;
            if (vL >= th) {
                ushort w16 = f2h(exp2f((sort2f(vL >> 16) - Mv) * L2E));
                if (pos < MAXL) { selrow[pos] = ((uint)w16 << 16) | (ib + c * 2); wp += h16f(w16); }
                ++pos;
            }
            if (vH >= th) {
                ushort w16 = f2h(exp2f((sort2f(vH >> 16) - Mv) * L2E));
                if (pos < MAXL) { selrow[pos] = ((uint)w16 << 16) | (ib + c * 2 + 1); wp += h16f(w16); }
                ++pos;
            }
        }
    }
#pragma unroll
    for (int off = 32; off >= 1; off >>= 1) wp += __shfl_xor(wp, off);
    return wp;
}

#define INS5(T0, T1, T2, T3, T4, P) { \
    uint m1_ = min(P, T0); T0 = max(P, T0); \
    uint m2_ = min(m1_, T1); T1 = max(m1_, T1); \
    uint m3_ = min(m2_, T2); T2 = max(m2_, T2); \
    uint m4_ = min(m3_, T3); T3 = max(m3_, T3); \
    T4 = max(m4_, T4); }

// ---------------------------------------------------------------------------
// attn v9: identical math to v8 + XCD-chunked block swizzle (each XCD serves
// 4 contiguous bh -> K/V L2-resident). template<PH>: PH=0 ablation runs only
// phase 1 (checksum kept live, written to ao which PH=2 later overwrites);
// PH=2 = full kernel.
// ---------------------------------------------------------------------------
template<int PH>
__global__ __launch_bounds__(512, 8) void attn_kernel(
    const ushort* __restrict__ qh, const ushort* __restrict__ kh,
    const ushort* __restrict__ vh, ushort* __restrict__ ao)
{
    __shared__ uint cand[QROWS * CSTRIDE];            // 21184 B
    __shared__ __align__(16) uint sel[QROWS][MAXL];   // 4096 B
    __shared__ __align__(16) ushort Sb1[2056];        // 4112 B (slow-path row)
    __shared__ float wsums[QROWS];
    __shared__ int   nks[QROWS];
    __shared__ int   missflag[QROWS];

    const int tid = threadIdx.x;
    const int wave = tid >> 6;
    const int lane = tid & 63;

    // XCD-chunked swizzle: wid%8 = XCD (round-robin dispatch) -> contiguous
    // flat range per XCD -> bh-locality in that XCD's L2. 4096 = 8*512.
    const int wid = blockIdx.y * gridDim.x + blockIdx.x;
    const int flat = (wid & 7) * 512 + (wid >> 3);
    const int bh = flat >> 7;            // 0..31
    const int q0 = (flat & 127) * QROWS; // 0..2032

    const int lr = lane & 15;
    const int lg = lane >> 4;
    const float L2E = 1.4426950408889634f;

    const ushort* Qb = qh + ((size_t)bh * NSEQ + q0) * HDIM;
    const ushort* Kb = kh + (size_t)bh * NSEQ * HDIM;

    f16x8 qf0 = *(const f16x8*)(Qb + lr * HDIM + lg * 8);
    f16x8 qf1 = *(const f16x8*)(Qb + lr * HDIM + 32 + lg * 8);

    // -------- Phase 1: scores + online per-lane 2x top-5 (64 streams/row) ---
    uint sA0 = 0, sA1 = 0, sA2 = 0, sA3 = 0, sA4 = 0;   // keys col+{0,1}
    uint sB0 = 0, sB1 = 0, sB2 = 0, sB3 = 0, sB4 = 0;   // keys col+{2,3}

    const int kwbase = wave * 256;
    const ushort* Kt0 = Kb + (size_t)kwbase * HDIM;
    f16x8 a0 = *(const f16x8*)(Kt0 + lr * HDIM + lg * 8);
    f16x8 a1 = *(const f16x8*)(Kt0 + lr * HDIM + 32 + lg * 8);

#pragma unroll
    for (int t = 0; t < 16; ++t) {
        f16x8 n0 = a0, n1 = a1;
        if (t < 15) {
            const ushort* Kn = Kb + (size_t)(kwbase + (t + 1) * 16) * HDIM;
            n0 = *(const f16x8*)(Kn + lr * HDIM + lg * 8);
            n1 = *(const f16x8*)(Kn + lr * HDIM + 32 + lg * 8);
        }
        f32x4 acc = {0.f, 0.f, 0.f, 0.f};
        acc = __builtin_amdgcn_mfma_f32_16x16x32_f16(a0, qf0, acc, 0, 0, 0);
        acc = __builtin_amdgcn_mfma_f32_16x16x32_f16(a1, qf1, acc, 0, 0, 0);
        const uint col = (uint)(kwbase + t * 16 + lg * 4);
        uint w0 = (uint)f2h(acc[0]) | ((uint)f2h(acc[1]) << 16);
        uint w1 = (uint)f2h(acc[2]) | ((uint)f2h(acc[3]) << 16);
        w0 = sm2(w0); w1 = sm2(w1);
        uint p;
        p = (w0 << 16) | col;               INS5(sA0, sA1, sA2, sA3, sA4, p);
        p = (w0 & 0xFFFF0000u) | (col + 1); INS5(sA0, sA1, sA2, sA3, sA4, p);
        p = (w1 << 16) | (col + 2);         INS5(sB0, sB1, sB2, sB3, sB4, p);
        p = (w1 & 0xFFFF0000u) | (col + 3); INS5(sB0, sB1, sB2, sB3, sB4, p);
        a0 = n0; a1 = n1;
    }

    {
        const int sid = wave * 8 + lg * 2;             // streams sid (A), sid+1 (B)
        const int cb = lr * CSTRIDE + sid;
        cand[cb +   0] = sA0; cand[cb +  66] = sA1; cand[cb + 132] = sA2;
        cand[cb + 198] = sA3; cand[cb + 264] = sA4;
        cand[cb +   1] = sB0; cand[cb +  67] = sB1; cand[cb + 133] = sB2;
        cand[cb + 199] = sB3; cand[cb + 265] = sB4;
    }
    __syncthreads();

    if constexpr (PH == 0) {
        // ablation: keep phase-1 results live (rule #17), then exit.
        uint cs2 = sA0 ^ sA1 ^ sA2 ^ sA3 ^ sA4 ^ sB0 ^ sB1 ^ sB2 ^ sB3 ^ sB4;
        cs2 ^= cand[(wave * 64 + lane) & 1023];
        size_t gt = ((size_t)wid * 512 + tid);
        ((uint*)ao)[gt] = cs2;    // ao fully overwritten by PH=2 afterwards
        return;
    }

    // -------- Phase 2: 2 rows per wave, one per 32-lane half ---------------
    const int halfid = lane >> 5;
    const int s = lane & 31;
    const int qr = wave * 2 + halfid;
    const int b = bh >> 3, hh = bh & 7;
    const ull LOMASK = 0xFFFFFFFFull;
    const ull HB = halfid ? ~LOMASK : LOMASK;

    uint c0, c1, c2, c3, c4, c5, c6, c7, c8, c9;
    {
        const int cb = qr * CSTRIDE + s;
        c0 = cand[cb];       c1 = cand[cb +  66]; c2 = cand[cb + 132];
        c3 = cand[cb + 198]; c4 = cand[cb + 264];
        c5 = cand[cb + 32];       c6 = cand[cb +  66 + 32]; c7 = cand[cb + 132 + 32];
        c8 = cand[cb + 198 + 32]; c9 = cand[cb + 264 + 32];
    }

    // row max (stream maxes include the true row max)
    uint mx = max(c0, c5);
#pragma unroll
    for (int off = 1; off <= 16; off <<= 1) mx = max(mx, (uint)__shfl_xor((int)mx, off));
    const float Mv = sort2f(mx >> 16);

    // binary search: 32nd largest of the 320-candidate sample
    uint lo = 0, hi = 0xFFFFu;
#pragma unroll
    for (int it = 0; it < 16; ++it) {
        uint mid = (lo + hi + 1) >> 1, M = mid << 16;
        int cnt = (c0 >= M) + (c1 >= M) + (c2 >= M) + (c3 >= M) + (c4 >= M)
                + (c5 >= M) + (c6 >= M) + (c7 >= M) + (c8 >= M) + (c9 >= M);
        ull m0 = __ballot(cnt & 1), m1 = __ballot(cnt & 2);
        ull m2 = __ballot(cnt & 4), m3 = __ballot(cnt & 8);
        int tH = (int)__popcll(m0 & HB) + 2 * (int)__popcll(m1 & HB)
               + 4 * (int)__popcll(m2 & HB) + 8 * (int)__popcll(m3 & HB);
        bool ge = tH >= LSEL;
        lo = ge ? mid : lo;
        hi = ge ? hi : mid - 1;
    }
    const uint th = lo << 16;

    // exactness: sample complete iff no stream's 5th-largest >= t-hat
    ull mm = __ballot((c4 >= th) || (c9 >= th));
    const bool missMy = (mm & HB) != 0ull;

    if (!missMy) {   // fast path: all selected elements are in c0..c3 / c5..c8
        int csel = (c0 >= th) + (c1 >= th) + (c2 >= th) + (c3 >= th)
                 + (c5 >= th) + (c6 >= th) + (c7 >= th) + (c8 >= th);
        ull below = ((1ull << lane) - 1ull) & HB;
        int pre = 0, tot = 0;
#pragma unroll
        for (int bb = 0; bb < 4; ++bb) {
            ull m = __ballot((csel >> bb) & 1);
            pre += (int)__popcll(m & below) << bb;
            tot += (int)__popcll(m & HB) << bb;
        }
        uint regs[8] = {c0, c1, c2, c3, c5, c6, c7, c8};
        float wp = 0.f;
        int k2 = 0;
#pragma unroll
        for (int i = 0; i < 8; ++i) {
            uint ui = regs[i];
            if (ui >= th) {
                ushort w16 = f2h(exp2f((sort2f(ui >> 16) - Mv) * L2E));
                int pos = pre + k2;
                if (pos < MAXL) { sel[qr][pos] = ((uint)w16 << 16) | (ui & 0xFFFFu); wp += h16f(w16); }
                ++k2;
            }
        }
#pragma unroll
        for (int off = 1; off <= 16; off <<= 1) wp += __shfl_xor(wp, off);
        if (s == 0) { wsums[qr] = wp; nks[qr] = (tot < MAXL) ? tot : MAXL; }
    }
    if (s == 0) missflag[qr] = missMy ? 1 : 0;
    __syncthreads();

    // -------- slow rows: bit-exact recompute + full-row exact select --------
    for (int r = 0; r < QROWS; ++r) {
        if (missflag[r]) {                       // block-uniform condition
            __syncthreads();                     // protect Sb1 reuse
#pragma unroll 4
            for (int t = 0; t < 16; ++t) {
                const ushort* Kt = Kb + (size_t)(kwbase + t * 16) * HDIM;
                f16x8 ra0 = *(const f16x8*)(Kt + lr * HDIM + lg * 8);
                f16x8 ra1 = *(const f16x8*)(Kt + lr * HDIM + 32 + lg * 8);
                f32x4 ac2 = {0.f, 0.f, 0.f, 0.f};
                ac2 = __builtin_amdgcn_mfma_f32_16x16x32_f16(ra0, qf0, ac2, 0, 0, 0);
                ac2 = __builtin_amdgcn_mfma_f32_16x16x32_f16(ra1, qf1, ac2, 0, 0, 0);
                if (lr == r) {
                    uint w0 = (uint)f2h(ac2[0]) | ((uint)f2h(ac2[1]) << 16);
                    uint w1 = (uint)f2h(ac2[2]) | ((uint)f2h(ac2[3]) << 16);
                    uint2 pk = {sm2(w0), sm2(w1)};
                    *(uint2*)&Sb1[kwbase + t * 16 + lg * 4] = pk;
                }
            }
            __syncthreads();
            if (wave == (r >> 1)) {              // wave-uniform
                const int h = r & 1;
                const float Mvr = __shfl(Mv, h * 32);
                const uint lor = (uint)__shfl((int)lo, h * 32);
                uint ft = full_thr(Sb1, lane, lor);
                uint thv = ft << 16;
                int cs = recount(Sb1, lane, thv);
                ull below64 = (1ull << lane) - 1ull;
                int preS = 0, totS = 0;
#pragma unroll
                for (int bb = 0; bb < 6; ++bb) {
                    ull m = __ballot((cs >> bb) & 1);
                    preS += (int)__popcll(m & below64) << bb;
                    totS += (int)__popcll(m) << bb;
                }
                float wr = extract_big(Sb1, lane, thv, Mvr, preS, &sel[r][0]);
                if (lane == 0) { wsums[r] = wr; nks[r] = (totS < MAXL) ? totS : MAXL; }
            }
        }
    }
    __syncthreads();

    // -------- sparse PV: half = row, 32 lanes x half2 dims, 8-deep unroll ---
    const __half2* V2 = reinterpret_cast<const __half2*>(vh + (size_t)bh * NSEQ * HDIM);
    const int dp = lane & 31;
    const int nkMy = nks[qr];
    const float wsMy = wsums[qr];
    const uint* selp = &sel[qr][0];

    float ox = 0.f, oy = 0.f;
    int j = 0;
    for (; j + 8 <= nkMy; j += 8) {
        uint e[8];
        *(uint4*)&e[0] = *(const uint4*)(selp + j);
        *(uint4*)&e[4] = *(const uint4*)(selp + j + 4);
        float2 vv[8];
        float ww[8];
#pragma unroll
        for (int i2 = 0; i2 < 8; ++i2) {
            int idx = (int)(e[i2] & 0xFFFFu);
            ww[i2] = h16f((ushort)(e[i2] >> 16));
            vv[i2] = __half22float2(V2[(size_t)idx * 32 + dp]);
        }
#pragma unroll
        for (int i2 = 0; i2 < 8; ++i2) { ox += ww[i2] * vv[i2].x; oy += ww[i2] * vv[i2].y; }
    }
    for (; j < nkMy; ++j) {
        uint e = selp[j];
        int idx = (int)(e & 0xFFFFu);
        float w = h16f((ushort)(e >> 16));
        float2 v0 = __half22float2(V2[(size_t)idx * 32 + dp]);
        ox += w * v0.x; oy += w * v0.y;
    }

    const float inv = 1.f / wsMy;
    uint opk = (uint)f2h(ox * inv) | ((uint)f2h(oy * inv) << 16);
    *(uint*)(ao + ((size_t)(b * NSEQ) + q0 + qr) * DMODEL + hh * HDIM + dp * 2) = opk;
}

// ---------------------------------------------------------------------------
// LN: out = LN(fc_raw + resid) * g + b ; 4 waves/block, 1 row/wave
// ---------------------------------------------------------------------------
__global__ __launch_bounds__(256) void ln_kernel(
    const float* __restrict__ fcr, const float* __restrict__ resid,
    const float* __restrict__ g, const float* __restrict__ bta, float* __restrict__ out)
{
    const int row = blockIdx.x * 4 + (threadIdx.x >> 6);
    const int lane = threadIdx.x & 63;
    const size_t base = (size_t)row * DMODEL + lane * 8;
    float4 xa = *(const float4*)(fcr + base);
    float4 xb = *(const float4*)(fcr + base + 4);
    float4 ra = *(const float4*)(resid + base);
    float4 rb = *(const float4*)(resid + base + 4);
    xa.x += ra.x; xa.y += ra.y; xa.z += ra.z; xa.w += ra.w;
    xb.x += rb.x; xb.y += rb.y; xb.z += rb.z; xb.w += rb.w;
    float sum = xa.x + xa.y + xa.z + xa.w + xb.x + xb.y + xb.z + xb.w;
    float sq = xa.x * xa.x + xa.y * xa.y + xa.z * xa.z + xa.w * xa.w
             + xb.x * xb.x + xb.y * xb.y + xb.z * xb.z + xb.w * xb.w;
#pragma unroll
    for (int off = 32; off >= 1; off >>= 1) {
        sum += __shfl_xor(sum, off);
        sq += __shfl_xor(sq, off);
    }
    float mean = sum * (1.f / 512.f);
    float var = sq * (1.f / 512.f) - mean * mean;
    float rstd = rsqrtf(var + 1e-6f);
    float4 ga = *(const float4*)(g + lane * 8);
    float4 gb = *(const float4*)(g + lane * 8 + 4);
    float4 ba = *(const float4*)(bta + lane * 8);
    float4 bb = *(const float4*)(bta + lane * 8 + 4);
    float4 oa, ob;
    oa.x = (xa.x - mean) * rstd * ga.x + ba.x;
    oa.y = (xa.y - mean) * rstd * ga.y + ba.y;
    oa.z = (xa.z - mean) * rstd * ga.z + ba.z;
    oa.w = (xa.w - mean) * rstd * ga.w + ba.w;
    ob.x = (xb.x - mean) * rstd * gb.x + bb.x;
    ob.y = (xb.y - mean) * rstd * gb.y + bb.y;
    ob.z = (xb.z - mean) * rstd * gb.z + bb.z;
    ob.w = (xb.w - mean) * rstd * gb.w + bb.w;
    *(float4*)(out + base) = oa;
    *(float4*)(out + base + 4) = ob;
}

extern "C" void kernel_launch(void* const* d_in, const int* in_sizes, int n_in,
                              void* d_out, int out_size, void* d_ws, size_t ws_size,
                              hipStream_t stream)
{
    (void)in_sizes; (void)n_in; (void)out_size; (void)ws_size;

    const float* q   = (const float*)d_in[0];
    const float* k   = (const float*)d_in[1];
    const float* v   = (const float*)d_in[2];
    const float* Wq  = (const float*)d_in[3];
    const float* Wk  = (const float*)d_in[4];
    const float* Wv  = (const float*)d_in[5];
    const float* Wfc = (const float*)d_in[6];
    const float* g   = (const float*)d_in[7];
    const float* b   = (const float*)d_in[8];
    float* out = (float*)d_out;

    const size_t SZ = (size_t)BATCH * NSEQ * DMODEL;      // 4,194,304
    const size_t WSZ = (size_t)DMODEL * DMODEL;           // 262,144
    ushort* w16 = (ushort*)d_ws;
    ushort* q16 = w16;
    ushort* k16 = w16 + SZ;
    ushort* v16 = w16 + 2 * SZ;
    ushort* Wt  = w16 + 3 * SZ;                           // 4 matrices
    ushort* qh  = Wt + 4 * WSZ;
    ushort* kh  = qh + SZ;
    ushort* vh  = kh + SZ;
    ushort* ao  = vh + SZ;
    float* fc_raw = (float*)d_ws;   // overlays q16+k16 (dead by fc time)

    cvtA_kernel<<<dim3(2048, 3), 256, 0, stream>>>(q, k, v, q16, k16, v16);
    cvtW_kernel<<<dim3(64, 4), 256, 0, stream>>>(Wq, Wk, Wv, Wfc, Wt);
    hgemm_kernel<0><<<dim3(128, 3), 256, 0, stream>>>(q16, k16, v16, Wt, qh, kh, vh, nullptr);
    // ablation: phase-1-only timing probe (output discarded; ao overwritten below)
    attn_kernel<0><<<dim3(NSEQ / QROWS, BATCH * NHEAD), 512, 0, stream>>>(qh, kh, vh, ao);
    attn_kernel<2><<<dim3(NSEQ / QROWS, BATCH * NHEAD), 512, 0, stream>>>(qh, kh, vh, ao);
    hgemm_kernel<1><<<dim3(128, 1), 256, 0, stream>>>(ao, nullptr, nullptr, Wt, nullptr, nullptr, nullptr, fc_raw);
    ln_kernel<<<(BATCH * NSEQ) / 4, 256, 0, stream>>>(fc_raw, q, g, b, out);
}

// Round 10
// 373.063 us; speedup vs baseline: 1.2699x; 1.2699x over previous
//
#include <hip/hip_runtime.h>
#include <hip/hip_fp16.h>

#define BATCH 4
#define NSEQ 2048
#define DMODEL 512
#define NHEAD 8
#define HDIM 64
#define LSEL 32
#define MAXL 64
#define QROWS 16
#define CSTRIDE 331   // cand row stride in u32 (5 levels x 66 + pad)

typedef __attribute__((ext_vector_type(8))) _Float16 f16x8;
typedef __attribute__((ext_vector_type(4))) float f32x4;
typedef unsigned long long ull;

__device__ inline ushort f2h(float x) { __half h = __float2half(x); return *reinterpret_cast<ushort*>(&h); }
__device__ inline float h16f(ushort u) { __half t; *reinterpret_cast<ushort*>(&t) = u; return __half2float(t); }
__device__ inline float sort2f(uint su) {
    ushort hb = (su & 0x8000u) ? (ushort)(su ^ 0x8000u) : (ushort)(su ^ 0xFFFFu);
    return h16f(hb);
}
// packed sortable map: per u16 half, neg -> ^0xFFFF, pos -> |0x8000
__device__ inline uint sm2(uint w) {
    uint s = (w >> 15) & 0x00010001u;
    uint m = (s << 15) - s;          // s * 0x7FFF without mul
    return w ^ (m | 0x80008000u);
}

// ---------------------------------------------------------------------------
// cvtA: fp32 -> fp16 copies of q,k,v
// ---------------------------------------------------------------------------
__global__ __launch_bounds__(256) void cvtA_kernel(
    const float* __restrict__ q, const float* __restrict__ k, const float* __restrict__ v,
    ushort* __restrict__ q16, ushort* __restrict__ k16, ushort* __restrict__ v16)
{
    const int z = blockIdx.y;
    const float* src = (z == 0) ? q : (z == 1) ? k : v;
    ushort* dst = (z == 0) ? q16 : (z == 1) ? k16 : v16;
    const size_t base = (size_t)blockIdx.x * 2048 + threadIdx.x * 4;
    float4 fa = *(const float4*)(src + base);
    float4 fb = *(const float4*)(src + base + 1024);
    ushort4 ha = {f2h(fa.x), f2h(fa.y), f2h(fa.z), f2h(fa.w)};
    ushort4 hb = {f2h(fb.x), f2h(fb.y), f2h(fb.z), f2h(fb.w)};
    *(ushort4*)(dst + base) = ha;
    *(ushort4*)(dst + base + 1024) = hb;
}

// ---------------------------------------------------------------------------
// cvtW: W[512][512] fp32 -> Wt[n][k] fp16 (transposed), 4 matrices
// ---------------------------------------------------------------------------
__global__ __launch_bounds__(256) void cvtW_kernel(
    const float* __restrict__ Wq, const float* __restrict__ Wk,
    const float* __restrict__ Wv, const float* __restrict__ Wfc,
    ushort* __restrict__ Wt)
{
    const int z = blockIdx.y;
    const float* W = (z == 0) ? Wq : (z == 1) ? Wk : (z == 2) ? Wv : Wfc;
    ushort* O = Wt + (size_t)z * DMODEL * DMODEL;
    const int gt = blockIdx.x * 256 + threadIdx.x;
    const int n = gt & 511;
    const int kc = (gt >> 9) * 16;
    uint pk[8];
#pragma unroll
    for (int i = 0; i < 8; ++i) {
        uint lo = f2h(W[(size_t)(kc + 2 * i) * DMODEL + n]);
        uint hi = f2h(W[(size_t)(kc + 2 * i + 1) * DMODEL + n]);
        pk[i] = lo | (hi << 16);
    }
    uint4 u0 = {pk[0], pk[1], pk[2], pk[3]};
    uint4 u1 = {pk[4], pk[5], pk[6], pk[7]};
    *(uint4*)(O + (size_t)n * DMODEL + kc) = u0;
    *(uint4*)(O + (size_t)n * DMODEL + kc + 8) = u1;
}

// ---------------------------------------------------------------------------
// hgemm: OUT[8192,512] = A16[8192,512] @ W (Wt stored [n][k] fp16).
// MODE 0: head-split fp16 out; z==0 (Q) pre-scaled by 0.125.
// MODE 1: fp32 row-major out.
// ---------------------------------------------------------------------------
template<int MODE>
__global__ __launch_bounds__(256, 2) void hgemm_kernel(
    const ushort* __restrict__ A0, const ushort* __restrict__ A1, const ushort* __restrict__ A2,
    const ushort* __restrict__ Wt,
    ushort* __restrict__ O0, ushort* __restrict__ O1, ushort* __restrict__ O2,
    float* __restrict__ Ofc)
{
    __shared__ ushort Ah[64][40];
    __shared__ ushort Bh[512][40];

    const int tid = threadIdx.x;
    const int wave = tid >> 6, lane = tid & 63;
    const int lr = lane & 15, lg = lane >> 4;
    const int bm = blockIdx.x * 64;
    const int z = blockIdx.y;

    const ushort* A16 = (MODE == 0) ? (z == 0 ? A0 : z == 1 ? A1 : A2) : A0;
    const ushort* Wz = Wt + (size_t)((MODE == 0) ? z : 3) * (DMODEL * DMODEL);

    f32x4 acc[4][8];
#pragma unroll
    for (int i = 0; i < 4; ++i)
#pragma unroll
        for (int j = 0; j < 8; ++j) acc[i][j] = (f32x4){0.f, 0.f, 0.f, 0.f};

    const int sar = tid >> 2, sak = (tid & 3) * 8;

    for (int k0 = 0; k0 < DMODEL; k0 += 32) {
        __syncthreads();
        *(uint4*)&Ah[sar][sak] = *(const uint4*)(A16 + (size_t)(bm + sar) * DMODEL + k0 + sak);
#pragma unroll
        for (int i = 0; i < 8; ++i) {
            int n = sar + 64 * i;
            *(uint4*)&Bh[n][sak] = *(const uint4*)(Wz + (size_t)n * DMODEL + k0 + sak);
        }
        __syncthreads();
        f16x8 af[4];
#pragma unroll
        for (int fr = 0; fr < 4; ++fr) af[fr] = *(const f16x8*)&Ah[fr * 16 + lr][lg * 8];
#pragma unroll
        for (int fc2 = 0; fc2 < 8; ++fc2) {
            f16x8 bf = *(const f16x8*)&Bh[wave * 128 + fc2 * 16 + lr][lg * 8];
#pragma unroll
            for (int fr = 0; fr < 4; ++fr)
                acc[fr][fc2] = __builtin_amdgcn_mfma_f32_16x16x32_f16(af[fr], bf, acc[fr][fc2], 0, 0, 0);
        }
    }

    if (MODE == 1) {
#pragma unroll
        for (int fr = 0; fr < 4; ++fr)
#pragma unroll
            for (int fc2 = 0; fc2 < 8; ++fc2)
#pragma unroll
                for (int r = 0; r < 4; ++r)
                    Ofc[(size_t)(bm + fr * 16 + lg * 4 + r) * DMODEL + wave * 128 + fc2 * 16 + lr] = acc[fr][fc2][r];
        return;
    }

    // MODE 0 epilogue: LDS transpose -> coalesced head-split fp16 stores
    const float osc = (z == 0) ? 0.125f : 1.0f;   // fold QK^T scale into Q
    ushort* O = (z == 0) ? O0 : (z == 1) ? O1 : O2;
    const int b = bm >> 11;
    const int nseq0 = bm & (NSEQ - 1);
    ushort* smw = (ushort*)&Bh[0][0] + wave * (64 * 72);
#pragma unroll
    for (int hp = 0; hp < 2; ++hp) {
        __syncthreads();
#pragma unroll
        for (int f4 = 0; f4 < 4; ++f4) {
            int fc2 = hp * 4 + f4;
            int nl = f4 * 16 + lr;
#pragma unroll
            for (int fr = 0; fr < 4; ++fr)
#pragma unroll
                for (int r = 0; r < 4; ++r)
                    smw[(fr * 16 + lg * 4 + r) * 72 + nl] = f2h(acc[fr][fc2][r] * osc);
        }
        __syncthreads();
        const int h = wave * 2 + hp;
        ushort* obase = O + ((size_t)(b * NHEAD + h) * NSEQ + nseq0) * HDIM;
#pragma unroll
        for (int i = 0; i < 8; ++i) {
            int m = i * 8 + (lane >> 3);
            int dc = (lane & 7) * 8;
            *(uint4*)(obase + (size_t)m * HDIM + dc) = *(const uint4*)(smw + m * 72 + dc);
        }
    }
}

// ---------------------------------------------------------------------------
// attention slow-path helpers (full-wave scans over a 2048-score row)
// ---------------------------------------------------------------------------
__device__ inline int wave_sum6(int c) {
    int tot = (int)__popcll(__ballot(c & 1));
    tot += (int)__popcll(__ballot(c & 2)) << 1;
    tot += (int)__popcll(__ballot(c & 4)) << 2;
    tot += (int)__popcll(__ballot(c & 8)) << 3;
    tot += (int)__popcll(__ballot(c & 16)) << 4;
    tot += (int)__popcll(__ballot(c & 32)) << 5;
    return tot;
}

__device__ uint full_thr(const ushort* Sr, int lane, uint lo0) {
    uint flo = lo0, fhi = 0xFFFFu;
#pragma unroll 1
    for (int it2 = 0; it2 < 16; ++it2) {
        uint mid = (flo + fhi + 1) >> 1, M = mid << 16;
        int cl = 0;
#pragma unroll
        for (int it = 0; it < 4; ++it) {
            uint4 r4 = *(const uint4*)(Sr + it * 512 + lane * 8);
            cl += ((r4.x << 16) >= M) + ((r4.x & 0xFFFF0000u) >= M);
            cl += ((r4.y << 16) >= M) + ((r4.y & 0xFFFF0000u) >= M);
            cl += ((r4.z << 16) >= M) + ((r4.z & 0xFFFF0000u) >= M);
            cl += ((r4.w << 16) >= M) + ((r4.w & 0xFFFF0000u) >= M);
        }
        bool ge = wave_sum6(cl) >= LSEL;
        flo = ge ? mid : flo;
        fhi = ge ? fhi : mid - 1;
    }
    return flo;
}

__device__ int recount(const ushort* Sr, int lane, uint th) {
    int cs = 0;
#pragma unroll
    for (int it = 0; it < 4; ++it) {
        uint4 r4 = *(const uint4*)(Sr + it * 512 + lane * 8);
        cs += ((r4.x << 16) >= th) + ((r4.x & 0xFFFF0000u) >= th);
        cs += ((r4.y << 16) >= th) + ((r4.y & 0xFFFF0000u) >= th);
        cs += ((r4.z << 16) >= th) + ((r4.z & 0xFFFF0000u) >= th);
        cs += ((r4.w << 16) >= th) + ((r4.w & 0xFFFF0000u) >= th);
    }
    return cs;
}

// full-row extraction (slow path): writes packed (w16<<16|idx)
__device__ float extract_big(const ushort* Sr, int lane, uint th, float Mv,
                             int pre, uint* selrow)
{
    const float L2E = 1.4426950408889634f;
    float wp = 0.f;
    int pos = pre;
#pragma unroll
    for (int it = 0; it < 4; ++it) {
        uint4 r4 = *(const uint4*)(Sr + it * 512 + lane * 8);
        uint ib = (uint)(it * 512 + lane * 8);
        uint wds[4] = {r4.x, r4.y, r4.z, r4.w};
#pragma unroll
        for (int c = 0; c < 4; ++c) {
            uint vL = wds[c] << 16, vH = wds[c] & 0xFFFF0000u;
            if (vL >= th) {
                ushort w16 = f2h(exp2f((sort2f(vL >> 16) - Mv) * L2E));
                if (pos < MAXL) { selrow[pos] = ((uint)w16 << 16) | (ib + c * 2); wp += h16f(w16); }
                ++pos;
            }
            if (vH >= th) {
                ushort w16 = f2h(exp2f((sort2f(vH >> 16) - Mv) * L2E));
                if (pos < MAXL) { selrow[pos] = ((uint)w16 << 16) | (ib + c * 2 + 1); wp += h16f(w16); }
                ++pos;
            }
        }
    }
#pragma unroll
    for (int off = 32; off >= 1; off >>= 1) wp += __shfl_xor(wp, off);
    return wp;
}

#define INS5(T0, T1, T2, T3, T4, P) { \
    uint m1_ = min(P, T0); T0 = max(P, T0); \
    uint m2_ = min(m1_, T1); T1 = max(m1_, T1); \
    uint m3_ = min(m2_, T2); T2 = max(m2_, T2); \
    uint m4_ = min(m3_, T3); T3 = max(m3_, T3); \
    T4 = max(m4_, T4); }

// ---------------------------------------------------------------------------
// attn v10: v9 math, despilled (launch_bounds(512,4) -> ~128 VGPR budget).
// PH=0 probe: K loads + MFMA only (checksum keeps work live).
// PH=1 probe: + cvt/sm2/pack + INS5 + cand write (full phase 1).
// PH=2: full kernel.
// ---------------------------------------------------------------------------
template<int PH>
__global__ __launch_bounds__(512, 4) void attn_kernel(
    const ushort* __restrict__ qh, const ushort* __restrict__ kh,
    const ushort* __restrict__ vh, ushort* __restrict__ ao)
{
    __shared__ uint cand[QROWS * CSTRIDE];            // 21184 B
    __shared__ __align__(16) uint sel[QROWS][MAXL];   // 4096 B
    __shared__ __align__(16) ushort Sb1[2056];        // 4112 B (slow-path row)
    __shared__ float wsums[QROWS];
    __shared__ int   nks[QROWS];
    __shared__ int   missflag[QROWS];

    const int tid = threadIdx.x;
    const int wave = tid >> 6;
    const int lane = tid & 63;

    // XCD-chunked swizzle (bijective: grid size divisible by 8)
    const int wid = blockIdx.y * gridDim.x + blockIdx.x;
    const int cpx = (gridDim.x * gridDim.y) >> 3;
    const int flat = (wid & 7) * cpx + (wid >> 3);
    const int bh = flat >> 7;
    const int q0 = (flat & 127) * QROWS;

    const int lr = lane & 15;
    const int lg = lane >> 4;
    const float L2E = 1.4426950408889634f;

    const ushort* Qb = qh + ((size_t)bh * NSEQ + q0) * HDIM;
    const ushort* Kb = kh + (size_t)bh * NSEQ * HDIM;

    f16x8 qf0 = *(const f16x8*)(Qb + lr * HDIM + lg * 8);
    f16x8 qf1 = *(const f16x8*)(Qb + lr * HDIM + 32 + lg * 8);

    // -------- Phase 1: scores + online per-lane 2x top-5 (64 streams/row) ---
    uint sA0 = 0, sA1 = 0, sA2 = 0, sA3 = 0, sA4 = 0;   // keys col+{0,1}
    uint sB0 = 0, sB1 = 0, sB2 = 0, sB3 = 0, sB4 = 0;   // keys col+{2,3}
    float csum = 0.f;                                   // PH=0 keep-alive

    const int kwbase = wave * 256;
    // per-lane K pointer; advances 1024 ushorts (16 keys) per iteration
    const ushort* kp = Kb + (size_t)kwbase * HDIM + lr * HDIM + lg * 8;
    f16x8 a0 = *(const f16x8*)kp;
    f16x8 a1 = *(const f16x8*)(kp + 32);

#pragma unroll
    for (int t = 0; t < 16; ++t) {
        f16x8 n0 = a0, n1 = a1;
        if (t < 15) {
            n0 = *(const f16x8*)(kp + 1024);
            n1 = *(const f16x8*)(kp + 1056);
        }
        f32x4 acc = {0.f, 0.f, 0.f, 0.f};
        acc = __builtin_amdgcn_mfma_f32_16x16x32_f16(a0, qf0, acc, 0, 0, 0);
        acc = __builtin_amdgcn_mfma_f32_16x16x32_f16(a1, qf1, acc, 0, 0, 0);
        if constexpr (PH == 0) {
            csum += acc[0] + acc[1] + acc[2] + acc[3];
        } else {
            const uint col = (uint)(kwbase + t * 16 + lg * 4);
            uint w0 = (uint)f2h(acc[0]) | ((uint)f2h(acc[1]) << 16);
            uint w1 = (uint)f2h(acc[2]) | ((uint)f2h(acc[3]) << 16);
            w0 = sm2(w0); w1 = sm2(w1);
            uint p;
            p = (w0 << 16) | col;               INS5(sA0, sA1, sA2, sA3, sA4, p);
            p = (w0 & 0xFFFF0000u) | (col + 1); INS5(sA0, sA1, sA2, sA3, sA4, p);
            p = (w1 << 16) | (col + 2);         INS5(sB0, sB1, sB2, sB3, sB4, p);
            p = (w1 & 0xFFFF0000u) | (col + 3); INS5(sB0, sB1, sB2, sB3, sB4, p);
        }
        a0 = n0; a1 = n1;
        kp += 1024;
    }

    if constexpr (PH == 0) {
        ((uint*)ao)[(size_t)wid * 512 + tid] = (uint)f2h(csum);
        return;
    }

    {
        const int sid = wave * 8 + lg * 2;             // streams sid (A), sid+1 (B)
        const int cb = lr * CSTRIDE + sid;
        cand[cb +   0] = sA0; cand[cb +  66] = sA1; cand[cb + 132] = sA2;
        cand[cb + 198] = sA3; cand[cb + 264] = sA4;
        cand[cb +   1] = sB0; cand[cb +  67] = sB1; cand[cb + 133] = sB2;
        cand[cb + 199] = sB3; cand[cb + 265] = sB4;
    }
    __syncthreads();

    if constexpr (PH == 1) {
        uint cs2 = sA0 ^ sA1 ^ sA2 ^ sA3 ^ sA4 ^ sB0 ^ sB1 ^ sB2 ^ sB3 ^ sB4;
        cs2 ^= cand[(wave * 64 + lane) & 1023];
        ((uint*)ao)[(size_t)wid * 512 + tid] = cs2;
        return;
    }

    // -------- Phase 2: 2 rows per wave, one per 32-lane half ---------------
    const int halfid = lane >> 5;
    const int s = lane & 31;
    const int qr = wave * 2 + halfid;
    const int b = bh >> 3, hh = bh & 7;
    const ull LOMASK = 0xFFFFFFFFull;
    const ull HB = halfid ? ~LOMASK : LOMASK;

    uint c0, c1, c2, c3, c4, c5, c6, c7, c8, c9;
    {
        const int cb = qr * CSTRIDE + s;
        c0 = cand[cb];       c1 = cand[cb +  66]; c2 = cand[cb + 132];
        c3 = cand[cb + 198]; c4 = cand[cb + 264];
        c5 = cand[cb + 32];       c6 = cand[cb +  66 + 32]; c7 = cand[cb + 132 + 32];
        c8 = cand[cb + 198 + 32]; c9 = cand[cb + 264 + 32];
    }

    // row max (stream maxes include the true row max)
    uint mx = max(c0, c5);
#pragma unroll
    for (int off = 1; off <= 16; off <<= 1) mx = max(mx, (uint)__shfl_xor((int)mx, off));
    const float Mv = sort2f(mx >> 16);

    // binary search: 32nd largest of the 320-candidate sample
    uint lo = 0, hi = 0xFFFFu;
#pragma unroll
    for (int it = 0; it < 16; ++it) {
        uint mid = (lo + hi + 1) >> 1, M = mid << 16;
        int cnt = (c0 >= M) + (c1 >= M) + (c2 >= M) + (c3 >= M) + (c4 >= M)
                + (c5 >= M) + (c6 >= M) + (c7 >= M) + (c8 >= M) + (c9 >= M);
        ull m0 = __ballot(cnt & 1), m1 = __ballot(cnt & 2);
        ull m2 = __ballot(cnt & 4), m3 = __ballot(cnt & 8);
        int tH = (int)__popcll(m0 & HB) + 2 * (int)__popcll(m1 & HB)
               + 4 * (int)__popcll(m2 & HB) + 8 * (int)__popcll(m3 & HB);
        bool ge = tH >= LSEL;
        lo = ge ? mid : lo;
        hi = ge ? hi : mid - 1;
    }
    const uint th = lo << 16;

    // exactness: sample complete iff no stream's 5th-largest >= t-hat
    ull mm = __ballot((c4 >= th) || (c9 >= th));
    const bool missMy = (mm & HB) != 0ull;

    if (!missMy) {   // fast path: all selected elements are in c0..c3 / c5..c8
        int csel = (c0 >= th) + (c1 >= th) + (c2 >= th) + (c3 >= th)
                 + (c5 >= th) + (c6 >= th) + (c7 >= th) + (c8 >= th);
        ull below = ((1ull << lane) - 1ull) & HB;
        int pre = 0, tot = 0;
#pragma unroll
        for (int bb = 0; bb < 4; ++bb) {
            ull m = __ballot((csel >> bb) & 1);
            pre += (int)__popcll(m & below) << bb;
            tot += (int)__popcll(m & HB) << bb;
        }
        uint regs[8] = {c0, c1, c2, c3, c5, c6, c7, c8};
        float wp = 0.f;
        int k2 = 0;
#pragma unroll
        for (int i = 0; i < 8; ++i) {
            uint ui = regs[i];
            if (ui >= th) {
                ushort w16 = f2h(exp2f((sort2f(ui >> 16) - Mv) * L2E));
                int pos = pre + k2;
                if (pos < MAXL) { sel[qr][pos] = ((uint)w16 << 16) | (ui & 0xFFFFu); wp += h16f(w16); }
                ++k2;
            }
        }
#pragma unroll
        for (int off = 1; off <= 16; off <<= 1) wp += __shfl_xor(wp, off);
        if (s == 0) { wsums[qr] = wp; nks[qr] = (tot < MAXL) ? tot : MAXL; }
    }
    if (s == 0) missflag[qr] = missMy ? 1 : 0;
    __syncthreads();

    // -------- slow rows: bit-exact recompute + full-row exact select --------
    for (int r = 0; r < QROWS; ++r) {
        if (missflag[r]) {                       // block-uniform condition
            __syncthreads();                     // protect Sb1 reuse
#pragma unroll 4
            for (int t = 0; t < 16; ++t) {
                const ushort* Kt = Kb + (size_t)(kwbase + t * 16) * HDIM;
                f16x8 ra0 = *(const f16x8*)(Kt + lr * HDIM + lg * 8);
                f16x8 ra1 = *(const f16x8*)(Kt + lr * HDIM + 32 + lg * 8);
                f32x4 ac2 = {0.f, 0.f, 0.f, 0.f};
                ac2 = __builtin_amdgcn_mfma_f32_16x16x32_f16(ra0, qf0, ac2, 0, 0, 0);
                ac2 = __builtin_amdgcn_mfma_f32_16x16x32_f16(ra1, qf1, ac2, 0, 0, 0);
                if (lr == r) {
                    uint w0 = (uint)f2h(ac2[0]) | ((uint)f2h(ac2[1]) << 16);
                    uint w1 = (uint)f2h(ac2[2]) | ((uint)f2h(ac2[3]) << 16);
                    uint2 pk = {sm2(w0), sm2(w1)};
                    *(uint2*)&Sb1[kwbase + t * 16 + lg * 4] = pk;
                }
            }
            __syncthreads();
            if (wave == (r >> 1)) {              // wave-uniform
                const int h = r & 1;
                const float Mvr = __shfl(Mv, h * 32);
                const uint lor = (uint)__shfl((int)lo, h * 32);
                uint ft = full_thr(Sb1, lane, lor);
                uint thv = ft << 16;
                int cs = recount(Sb1, lane, thv);
                ull below64 = (1ull << lane) - 1ull;
                int preS = 0, totS = 0;
#pragma unroll
                for (int bb = 0; bb < 6; ++bb) {
                    ull m = __ballot((cs >> bb) & 1);
                    preS += (int)__popcll(m & below64) << bb;
                    totS += (int)__popcll(m) << bb;
                }
                float wr = extract_big(Sb1, lane, thv, Mvr, preS, &sel[r][0]);
                if (lane == 0) { wsums[r] = wr; nks[r] = (totS < MAXL) ? totS : MAXL; }
            }
        }
    }
    __syncthreads();

    // -------- sparse PV: half = row, 32 lanes x half2 dims, 8-deep unroll ---
    const __half2* V2 = reinterpret_cast<const __half2*>(vh + (size_t)bh * NSEQ * HDIM);
    const int dp = lane & 31;
    const int nkMy = nks[qr];
    const float wsMy = wsums[qr];
    const uint* selp = &sel[qr][0];

    float ox = 0.f, oy = 0.f;
    int j = 0;
    for (; j + 8 <= nkMy; j += 8) {
        uint e[8];
        *(uint4*)&e[0] = *(const uint4*)(selp + j);
        *(uint4*)&e[4] = *(const uint4*)(selp + j + 4);
        float2 vv[8];
        float ww[8];
#pragma unroll
        for (int i2 = 0; i2 < 8; ++i2) {
            int idx = (int)(e[i2] & 0xFFFFu);
            ww[i2] = h16f((ushort)(e[i2] >> 16));
            vv[i2] = __half22float2(V2[(size_t)idx * 32 + dp]);
        }
#pragma unroll
        for (int i2 = 0; i2 < 8; ++i2) { ox += ww[i2] * vv[i2].x; oy += ww[i2] * vv[i2].y; }
    }
    for (; j < nkMy; ++j) {
        uint e = selp[j];
        int idx = (int)(e & 0xFFFFu);
        float w = h16f((ushort)(e >> 16));
        float2 v0 = __half22float2(V2[(size_t)idx * 32 + dp]);
        ox += w * v0.x; oy += w * v0.y;
    }

    const float inv = 1.f / wsMy;
    uint opk = (uint)f2h(ox * inv) | ((uint)f2h(oy * inv) << 16);
    *(uint*)(ao + ((size_t)(b * NSEQ) + q0 + qr) * DMODEL + hh * HDIM + dp * 2) = opk;
}

// ---------------------------------------------------------------------------
// LN: out = LN(fc_raw + resid) * g + b ; 4 waves/block, 1 row/wave
// ---------------------------------------------------------------------------
__global__ __launch_bounds__(256) void ln_kernel(
    const float* __restrict__ fcr, const float* __restrict__ resid,
    const float* __restrict__ g, const float* __restrict__ bta, float* __restrict__ out)
{
    const int row = blockIdx.x * 4 + (threadIdx.x >> 6);
    const int lane = threadIdx.x & 63;
    const size_t base = (size_t)row * DMODEL + lane * 8;
    float4 xa = *(const float4*)(fcr + base);
    float4 xb = *(const float4*)(fcr + base + 4);
    float4 ra = *(const float4*)(resid + base);
    float4 rb = *(const float4*)(resid + base + 4);
    xa.x += ra.x; xa.y += ra.y; xa.z += ra.z; xa.w += ra.w;
    xb.x += rb.x; xb.y += rb.y; xb.z += rb.z; xb.w += rb.w;
    float sum = xa.x + xa.y + xa.z + xa.w + xb.x + xb.y + xb.z + xb.w;
    float sq = xa.x * xa.x + xa.y * xa.y + xa.z * xa.z + xa.w * xa.w
             + xb.x * xb.x + xb.y * xb.y + xb.z * xb.z + xb.w * xb.w;
#pragma unroll
    for (int off = 32; off >= 1; off >>= 1) {
        sum += __shfl_xor(sum, off);
        sq += __shfl_xor(sq, off);
    }
    float mean = sum * (1.f / 512.f);
    float var = sq * (1.f / 512.f) - mean * mean;
    float rstd = rsqrtf(var + 1e-6f);
    float4 ga = *(const float4*)(g + lane * 8);
    float4 gb = *(const float4*)(g + lane * 8 + 4);
    float4 ba = *(const float4*)(bta + lane * 8);
    float4 bb = *(const float4*)(bta + lane * 8 + 4);
    float4 oa, ob;
    oa.x = (xa.x - mean) * rstd * ga.x + ba.x;
    oa.y = (xa.y - mean) * rstd * ga.y + ba.y;
    oa.z = (xa.z - mean) * rstd * ga.z + ba.z;
    oa.w = (xa.w - mean) * rstd * ga.w + ba.w;
    ob.x = (xb.x - mean) * rstd * gb.x + bb.x;
    ob.y = (xb.y - mean) * rstd * gb.y + bb.y;
    ob.z = (xb.z - mean) * rstd * gb.z + bb.z;
    ob.w = (xb.w - mean) * rstd * gb.w + bb.w;
    *(float4*)(out + base) = oa;
    *(float4*)(out + base + 4) = ob;
}

extern "C" void kernel_launch(void* const* d_in, const int* in_sizes, int n_in,
                              void* d_out, int out_size, void* d_ws, size_t ws_size,
                              hipStream_t stream)
{
    (void)in_sizes; (void)n_in; (void)out_size; (void)ws_size;

    const float* q   = (const float*)d_in[0];
    const float* k   = (const float*)d_in[1];
    const float* v   = (const float*)d_in[2];
    const float* Wq  = (const float*)d_in[3];
    const float* Wk  = (const float*)d_in[4];
    const float* Wv  = (const float*)d_in[5];
    const float* Wfc = (const float*)d_in[6];
    const float* g   = (const float*)d_in[7];
    const float* b   = (const float*)d_in[8];
    float* out = (float*)d_out;

    const size_t SZ = (size_t)BATCH * NSEQ * DMODEL;      // 4,194,304
    const size_t WSZ = (size_t)DMODEL * DMODEL;           // 262,144
    ushort* w16 = (ushort*)d_ws;
    ushort* q16 = w16;
    ushort* k16 = w16 + SZ;
    ushort* v16 = w16 + 2 * SZ;
    ushort* Wt  = w16 + 3 * SZ;                           // 4 matrices
    ushort* qh  = Wt + 4 * WSZ;
    ushort* kh  = qh + SZ;
    ushort* vh  = kh + SZ;
    ushort* ao  = vh + SZ;
    float* fc_raw = (float*)d_ws;   // overlays q16+k16 (dead by fc time)

    cvtA_kernel<<<dim3(2048, 3), 256, 0, stream>>>(q, k, v, q16, k16, v16);
    cvtW_kernel<<<dim3(64, 4), 256, 0, stream>>>(Wq, Wk, Wv, Wfc, Wt);
    hgemm_kernel<0><<<dim3(128, 3), 256, 0, stream>>>(q16, k16, v16, Wt, qh, kh, vh, nullptr);
    // quarter-grid probes (bh 0..7): outputs land in ao and are fully
    // overwritten by the PH=2 launch below.
    attn_kernel<0><<<dim3(128, 8), 512, 0, stream>>>(qh, kh, vh, ao);
    attn_kernel<1><<<dim3(128, 8), 512, 0, stream>>>(qh, kh, vh, ao);
    attn_kernel<2><<<dim3(NSEQ / QROWS, BATCH * NHEAD), 512, 0, stream>>>(qh, kh, vh, ao);
    hgemm_kernel<1><<<dim3(128, 1), 256, 0, stream>>>(ao, nullptr, nullptr, Wt, nullptr, nullptr, nullptr, fc_raw);
    ln_kernel<<<(BATCH * NSEQ) / 4, 256, 0, stream>>>(fc_raw, q, g, b, out);
}

// Round 11
// 320.874 us; speedup vs baseline: 1.4764x; 1.1626x over previous
//
#include <hip/hip_runtime.h>
#include <hip/hip_fp16.h>

#define BATCH 4
#define NSEQ 2048
#define DMODEL 512
#define NHEAD 8
#define HDIM 64
#define LSEL 32
#define MAXL 64
#define QROWS 16
#define CSTRIDE 331   // cand row stride in u32 (5 levels x 66 + pad)

typedef __attribute__((ext_vector_type(8))) _Float16 f16x8;
typedef __attribute__((ext_vector_type(4))) float f32x4;
typedef unsigned long long ull;

__device__ inline ushort f2h(float x) { __half h = __float2half(x); return *reinterpret_cast<ushort*>(&h); }
__device__ inline float h16f(ushort u) { __half t; *reinterpret_cast<ushort*>(&t) = u; return __half2float(t); }
__device__ inline float sort2f(uint su) {
    ushort hb = (su & 0x8000u) ? (ushort)(su ^ 0x8000u) : (ushort)(su ^ 0xFFFFu);
    return h16f(hb);
}
// packed sortable map: per u16 half, neg -> ^0xFFFF, pos -> |0x8000
__device__ inline uint sm2(uint w) {
    uint s = (w >> 15) & 0x00010001u;
    uint m = (s << 15) - s;
    return w ^ (m | 0x80008000u);
}
// LDS K-tile swizzle: XOR key-row low bits into 16B-slot bits (bank balance)
__device__ inline uint swzb(uint b) { return b ^ (((b >> 7) & 7u) << 4); }

// ---------------------------------------------------------------------------
// cvtA: fp32 -> fp16 copies of q,k,v
// ---------------------------------------------------------------------------
__global__ __launch_bounds__(256) void cvtA_kernel(
    const float* __restrict__ q, const float* __restrict__ k, const float* __restrict__ v,
    ushort* __restrict__ q16, ushort* __restrict__ k16, ushort* __restrict__ v16)
{
    const int z = blockIdx.y;
    const float* src = (z == 0) ? q : (z == 1) ? k : v;
    ushort* dst = (z == 0) ? q16 : (z == 1) ? k16 : v16;
    const size_t base = (size_t)blockIdx.x * 2048 + threadIdx.x * 4;
    float4 fa = *(const float4*)(src + base);
    float4 fb = *(const float4*)(src + base + 1024);
    ushort4 ha = {f2h(fa.x), f2h(fa.y), f2h(fa.z), f2h(fa.w)};
    ushort4 hb = {f2h(fb.x), f2h(fb.y), f2h(fb.z), f2h(fb.w)};
    *(ushort4*)(dst + base) = ha;
    *(ushort4*)(dst + base + 1024) = hb;
}

// ---------------------------------------------------------------------------
// cvtW: W[512][512] fp32 -> Wt[n][k] fp16 (transposed), 4 matrices
// ---------------------------------------------------------------------------
__global__ __launch_bounds__(256) void cvtW_kernel(
    const float* __restrict__ Wq, const float* __restrict__ Wk,
    const float* __restrict__ Wv, const float* __restrict__ Wfc,
    ushort* __restrict__ Wt)
{
    const int z = blockIdx.y;
    const float* W = (z == 0) ? Wq : (z == 1) ? Wk : (z == 2) ? Wv : Wfc;
    ushort* O = Wt + (size_t)z * DMODEL * DMODEL;
    const int gt = blockIdx.x * 256 + threadIdx.x;
    const int n = gt & 511;
    const int kc = (gt >> 9) * 16;
    uint pk[8];
#pragma unroll
    for (int i = 0; i < 8; ++i) {
        uint lo = f2h(W[(size_t)(kc + 2 * i) * DMODEL + n]);
        uint hi = f2h(W[(size_t)(kc + 2 * i + 1) * DMODEL + n]);
        pk[i] = lo | (hi << 16);
    }
    uint4 u0 = {pk[0], pk[1], pk[2], pk[3]};
    uint4 u1 = {pk[4], pk[5], pk[6], pk[7]};
    *(uint4*)(O + (size_t)n * DMODEL + kc) = u0;
    *(uint4*)(O + (size_t)n * DMODEL + kc + 8) = u1;
}

// ---------------------------------------------------------------------------
// hgemm: OUT[8192,512] = A16[8192,512] @ W (Wt stored [n][k] fp16).
// MODE 0: head-split fp16 out; z==0 (Q) pre-scaled by 0.125.
// MODE 1: fp32 row-major out.
// ---------------------------------------------------------------------------
template<int MODE>
__global__ __launch_bounds__(256, 2) void hgemm_kernel(
    const ushort* __restrict__ A0, const ushort* __restrict__ A1, const ushort* __restrict__ A2,
    const ushort* __restrict__ Wt,
    ushort* __restrict__ O0, ushort* __restrict__ O1, ushort* __restrict__ O2,
    float* __restrict__ Ofc)
{
    __shared__ ushort Ah[64][40];
    __shared__ ushort Bh[512][40];

    const int tid = threadIdx.x;
    const int wave = tid >> 6, lane = tid & 63;
    const int lr = lane & 15, lg = lane >> 4;
    const int bm = blockIdx.x * 64;
    const int z = blockIdx.y;

    const ushort* A16 = (MODE == 0) ? (z == 0 ? A0 : z == 1 ? A1 : A2) : A0;
    const ushort* Wz = Wt + (size_t)((MODE == 0) ? z : 3) * (DMODEL * DMODEL);

    f32x4 acc[4][8];
#pragma unroll
    for (int i = 0; i < 4; ++i)
#pragma unroll
        for (int j = 0; j < 8; ++j) acc[i][j] = (f32x4){0.f, 0.f, 0.f, 0.f};

    const int sar = tid >> 2, sak = (tid & 3) * 8;

    for (int k0 = 0; k0 < DMODEL; k0 += 32) {
        __syncthreads();
        *(uint4*)&Ah[sar][sak] = *(const uint4*)(A16 + (size_t)(bm + sar) * DMODEL + k0 + sak);
#pragma unroll
        for (int i = 0; i < 8; ++i) {
            int n = sar + 64 * i;
            *(uint4*)&Bh[n][sak] = *(const uint4*)(Wz + (size_t)n * DMODEL + k0 + sak);
        }
        __syncthreads();
        f16x8 af[4];
#pragma unroll
        for (int fr = 0; fr < 4; ++fr) af[fr] = *(const f16x8*)&Ah[fr * 16 + lr][lg * 8];
#pragma unroll
        for (int fc2 = 0; fc2 < 8; ++fc2) {
            f16x8 bf = *(const f16x8*)&Bh[wave * 128 + fc2 * 16 + lr][lg * 8];
#pragma unroll
            for (int fr = 0; fr < 4; ++fr)
                acc[fr][fc2] = __builtin_amdgcn_mfma_f32_16x16x32_f16(af[fr], bf, acc[fr][fc2], 0, 0, 0);
        }
    }

    if (MODE == 1) {
#pragma unroll
        for (int fr = 0; fr < 4; ++fr)
#pragma unroll
            for (int fc2 = 0; fc2 < 8; ++fc2)
#pragma unroll
                for (int r = 0; r < 4; ++r)
                    Ofc[(size_t)(bm + fr * 16 + lg * 4 + r) * DMODEL + wave * 128 + fc2 * 16 + lr] = acc[fr][fc2][r];
        return;
    }

    // MODE 0 epilogue: LDS transpose -> coalesced head-split fp16 stores
    const float osc = (z == 0) ? 0.125f : 1.0f;   // fold QK^T scale into Q
    ushort* O = (z == 0) ? O0 : (z == 1) ? O1 : O2;
    const int b = bm >> 11;
    const int nseq0 = bm & (NSEQ - 1);
    ushort* smw = (ushort*)&Bh[0][0] + wave * (64 * 72);
#pragma unroll
    for (int hp = 0; hp < 2; ++hp) {
        __syncthreads();
#pragma unroll
        for (int f4 = 0; f4 < 4; ++f4) {
            int fc2 = hp * 4 + f4;
            int nl = f4 * 16 + lr;
#pragma unroll
            for (int fr = 0; fr < 4; ++fr)
#pragma unroll
                for (int r = 0; r < 4; ++r)
                    smw[(fr * 16 + lg * 4 + r) * 72 + nl] = f2h(acc[fr][fc2][r] * osc);
        }
        __syncthreads();
        const int h = wave * 2 + hp;
        ushort* obase = O + ((size_t)(b * NHEAD + h) * NSEQ + nseq0) * HDIM;
#pragma unroll
        for (int i = 0; i < 8; ++i) {
            int m = i * 8 + (lane >> 3);
            int dc = (lane & 7) * 8;
            *(uint4*)(obase + (size_t)m * HDIM + dc) = *(const uint4*)(smw + m * 72 + dc);
        }
    }
}

// ---------------------------------------------------------------------------
// attention slow-path helpers (full-wave scans over a 2048-score row)
// ---------------------------------------------------------------------------
__device__ inline int wave_sum6(int c) {
    int tot = (int)__popcll(__ballot(c & 1));
    tot += (int)__popcll(__ballot(c & 2)) << 1;
    tot += (int)__popcll(__ballot(c & 4)) << 2;
    tot += (int)__popcll(__ballot(c & 8)) << 3;
    tot += (int)__popcll(__ballot(c & 16)) << 4;
    tot += (int)__popcll(__ballot(c & 32)) << 5;
    return tot;
}

__device__ uint full_thr(const ushort* Sr, int lane, uint lo0) {
    uint flo = lo0, fhi = 0xFFFFu;
#pragma unroll 1
    for (int it2 = 0; it2 < 16; ++it2) {
        uint mid = (flo + fhi + 1) >> 1, M = mid << 16;
        int cl = 0;
#pragma unroll
        for (int it = 0; it < 4; ++it) {
            uint4 r4 = *(const uint4*)(Sr + it * 512 + lane * 8);
            cl += ((r4.x << 16) >= M) + ((r4.x & 0xFFFF0000u) >= M);
            cl += ((r4.y << 16) >= M) + ((r4.y & 0xFFFF0000u) >= M);
            cl += ((r4.z << 16) >= M) + ((r4.z & 0xFFFF0000u) >= M);
            cl += ((r4.w << 16) >= M) + ((r4.w & 0xFFFF0000u) >= M);
        }
        bool ge = wave_sum6(cl) >= LSEL;
        flo = ge ? mid : flo;
        fhi = ge ? fhi : mid - 1;
    }
    return flo;
}

__device__ int recount(const ushort* Sr, int lane, uint th) {
    int cs = 0;
#pragma unroll
    for (int it = 0; it < 4; ++it) {
        uint4 r4 = *(const uint4*)(Sr + it * 512 + lane * 8);
        cs += ((r4.x << 16) >= th) + ((r4.x & 0xFFFF0000u) >= th);
        cs += ((r4.y << 16) >= th) + ((r4.y & 0xFFFF0000u) >= th);
        cs += ((r4.z << 16) >= th) + ((r4.z & 0xFFFF0000u) >= th);
        cs += ((r4.w << 16) >= th) + ((r4.w & 0xFFFF0000u) >= th);
    }
    return cs;
}

// full-row extraction (slow path): writes packed (w16<<16|idx)
__device__ float extract_big(const ushort* Sr, int lane, uint th, float Mv,
                             int pre, uint* selrow)
{
    const float L2E = 1.4426950408889634f;
    float wp = 0.f;
    int pos = pre;
#pragma unroll
    for (int it = 0; it < 4; ++it) {
        uint4 r4 = *(const uint4*)(Sr + it * 512 + lane * 8);
        uint ib = (uint)(it * 512 + lane * 8);
        uint wds[4] = {r4.x, r4.y, r4.z, r4.w};
#pragma unroll
        for (int c = 0; c < 4; ++c) {
            uint vL = wds[c] << 16, vH = wds[c] & 0xFFFF0000u;
            if (vL >= th) {
                ushort w16 = f2h(exp2f((sort2f(vL >> 16) - Mv) * L2E));
                if (pos < MAXL) { selrow[pos] = ((uint)w16 << 16) | (ib + c * 2); wp += h16f(w16); }
                ++pos;
            }
            if (vH >= th) {
                ushort w16 = f2h(exp2f((sort2f(vH >> 16) - Mv) * L2E));
                if (pos < MAXL) { selrow[pos] = ((uint)w16 << 16) | (ib + c * 2 + 1); wp += h16f(w16); }
                ++pos;
            }
        }
    }
#pragma unroll
    for (int off = 32; off >= 1; off >>= 1) wp += __shfl_xor(wp, off);
    return wp;
}

#define INS5(T0, T1, T2, T3, T4, P) { \
    uint m1_ = min(P, T0); T0 = max(P, T0); \
    uint m2_ = min(m1_, T1); T1 = max(m1_, T1); \
    uint m3_ = min(m2_, T2); T2 = max(m2_, T2); \
    uint m4_ = min(m3_, T3); T3 = max(m3_, T3); \
    T4 = max(m4_, T4); }

// ---------------------------------------------------------------------------
// attn v11: phase 1 rebuilt around cooperative LDS K-staging:
//  - 128-key tile (16KB) staged per block by all 512 threads (dense 32B/thread
//    coalesced loads), one-tile register prefetch hides global latency;
//  - waves read 16-key MFMA fragments from LDS with XOR swizzle (bank-balanced);
//  - streams: key = t*128 + wave*16 + lg*4 + reg -> same 64-streams-of-32
//    statistics as v8; cand/phase-2/slow-path machinery unchanged.
// ---------------------------------------------------------------------------
__global__ __launch_bounds__(512, 4) void attn_kernel(
    const ushort* __restrict__ qh, const ushort* __restrict__ kh,
    const ushort* __restrict__ vh, ushort* __restrict__ ao)
{
    __shared__ __align__(16) ushort Ktile[8192];      // 128 keys x 64 halfs, 16KB
    __shared__ uint cand[QROWS * CSTRIDE];            // 21184 B
    __shared__ __align__(16) uint sel[QROWS][MAXL];   // 4096 B
    __shared__ __align__(16) ushort Sb1[2056];        // 4112 B (slow-path row)
    __shared__ float wsums[QROWS];
    __shared__ int   nks[QROWS];
    __shared__ int   missflag[QROWS];

    const int tid = threadIdx.x;
    const int wave = tid >> 6;
    const int lane = tid & 63;

    // XCD-chunked swizzle (bijective: grid size divisible by 8)
    const int wid = blockIdx.y * gridDim.x + blockIdx.x;
    const int cpx = (gridDim.x * gridDim.y) >> 3;
    const int flat = (wid & 7) * cpx + (wid >> 3);
    const int bh = flat >> 7;
    const int q0 = (flat & 127) * QROWS;

    const int lr = lane & 15;
    const int lg = lane >> 4;
    const float L2E = 1.4426950408889634f;

    const ushort* Qb = qh + ((size_t)bh * NSEQ + q0) * HDIM;
    const ushort* Kb = kh + (size_t)bh * NSEQ * HDIM;

    f16x8 qf0 = *(const f16x8*)(Qb + lr * HDIM + lg * 8);
    f16x8 qf1 = *(const f16x8*)(Qb + lr * HDIM + 32 + lg * 8);

    // -------- Phase 1: staged scores + online per-lane 2x top-5 -------------
    uint sA0 = 0, sA1 = 0, sA2 = 0, sA3 = 0, sA4 = 0;   // keys col+{0,1}
    uint sB0 = 0, sB1 = 0, sB2 = 0, sB3 = 0, sB4 = 0;   // keys col+{2,3}

    // staging: thread covers 32B of the 16KB tile
    uint4 r0, r1;
    {
        const ushort* src = Kb + tid * 16;
        r0 = *(const uint4*)(src);
        r1 = *(const uint4*)(src + 8);
    }
    const uint wb0 = swzb((uint)tid * 32) >> 1;        // half-index
    const uint wb1 = swzb((uint)tid * 32 + 16) >> 1;
    const uint klocal = (uint)(wave * 16 + lr);
    const uint rb0 = swzb(klocal * 128 + lg * 16) >> 1;
    const uint rb1 = swzb(klocal * 128 + 64 + lg * 16) >> 1;

#pragma unroll 1
    for (int t = 0; t < 16; ++t) {
        __syncthreads();                 // all reads of previous tile done
        *(uint4*)&Ktile[wb0] = r0;
        *(uint4*)&Ktile[wb1] = r1;
        __syncthreads();                 // tile t visible
        if (t < 15) {
            const ushort* src = Kb + (t + 1) * 8192 + tid * 16;
            r0 = *(const uint4*)(src);
            r1 = *(const uint4*)(src + 8);
        }
        f16x8 a0 = *(const f16x8*)&Ktile[rb0];
        f16x8 a1 = *(const f16x8*)&Ktile[rb1];
        f32x4 acc = {0.f, 0.f, 0.f, 0.f};
        acc = __builtin_amdgcn_mfma_f32_16x16x32_f16(a0, qf0, acc, 0, 0, 0);
        acc = __builtin_amdgcn_mfma_f32_16x16x32_f16(a1, qf1, acc, 0, 0, 0);
        const uint col = (uint)(t * 128 + wave * 16 + lg * 4);
        uint w0 = (uint)f2h(acc[0]) | ((uint)f2h(acc[1]) << 16);
        uint w1 = (uint)f2h(acc[2]) | ((uint)f2h(acc[3]) << 16);
        w0 = sm2(w0); w1 = sm2(w1);
        uint p;
        p = (w0 << 16) | col;               INS5(sA0, sA1, sA2, sA3, sA4, p);
        p = (w0 & 0xFFFF0000u) | (col + 1); INS5(sA0, sA1, sA2, sA3, sA4, p);
        p = (w1 << 16) | (col + 2);         INS5(sB0, sB1, sB2, sB3, sB4, p);
        p = (w1 & 0xFFFF0000u) | (col + 3); INS5(sB0, sB1, sB2, sB3, sB4, p);
    }

    {
        const int sid = wave * 8 + lg * 2;             // streams sid (A), sid+1 (B)
        const int cb = lr * CSTRIDE + sid;
        cand[cb +   0] = sA0; cand[cb +  66] = sA1; cand[cb + 132] = sA2;
        cand[cb + 198] = sA3; cand[cb + 264] = sA4;
        cand[cb +   1] = sB0; cand[cb +  67] = sB1; cand[cb + 133] = sB2;
        cand[cb + 199] = sB3; cand[cb + 265] = sB4;
    }
    __syncthreads();

    // -------- Phase 2: 2 rows per wave, one per 32-lane half ---------------
    const int halfid = lane >> 5;
    const int s = lane & 31;
    const int qr = wave * 2 + halfid;
    const int b = bh >> 3, hh = bh & 7;
    const ull LOMASK = 0xFFFFFFFFull;
    const ull HB = halfid ? ~LOMASK : LOMASK;

    uint c0, c1, c2, c3, c4, c5, c6, c7, c8, c9;
    {
        const int cb = qr * CSTRIDE + s;
        c0 = cand[cb];       c1 = cand[cb +  66]; c2 = cand[cb + 132];
        c3 = cand[cb + 198]; c4 = cand[cb + 264];
        c5 = cand[cb + 32];       c6 = cand[cb +  66 + 32]; c7 = cand[cb + 132 + 32];
        c8 = cand[cb + 198 + 32]; c9 = cand[cb + 264 + 32];
    }

    // row max (stream maxes include the true row max)
    uint mx = max(c0, c5);
#pragma unroll
    for (int off = 1; off <= 16; off <<= 1) mx = max(mx, (uint)__shfl_xor((int)mx, off));
    const float Mv = sort2f(mx >> 16);

    // binary search: 32nd largest of the 320-candidate sample
    uint lo = 0, hi = 0xFFFFu;
#pragma unroll
    for (int it = 0; it < 16; ++it) {
        uint mid = (lo + hi + 1) >> 1, M = mid << 16;
        int cnt = (c0 >= M) + (c1 >= M) + (c2 >= M) + (c3 >= M) + (c4 >= M)
                + (c5 >= M) + (c6 >= M) + (c7 >= M) + (c8 >= M) + (c9 >= M);
        ull m0 = __ballot(cnt & 1), m1 = __ballot(cnt & 2);
        ull m2 = __ballot(cnt & 4), m3 = __ballot(cnt & 8);
        int tH = (int)__popcll(m0 & HB) + 2 * (int)__popcll(m1 & HB)
               + 4 * (int)__popcll(m2 & HB) + 8 * (int)__popcll(m3 & HB);
        bool ge = tH >= LSEL;
        lo = ge ? mid : lo;
        hi = ge ? hi : mid - 1;
    }
    const uint th = lo << 16;

    // exactness: sample complete iff no stream's 5th-largest >= t-hat
    ull mm = __ballot((c4 >= th) || (c9 >= th));
    const bool missMy = (mm & HB) != 0ull;

    if (!missMy) {   // fast path: all selected elements are in c0..c3 / c5..c8
        int csel = (c0 >= th) + (c1 >= th) + (c2 >= th) + (c3 >= th)
                 + (c5 >= th) + (c6 >= th) + (c7 >= th) + (c8 >= th);
        ull below = ((1ull << lane) - 1ull) & HB;
        int pre = 0, tot = 0;
#pragma unroll
        for (int bb = 0; bb < 4; ++bb) {
            ull m = __ballot((csel >> bb) & 1);
            pre += (int)__popcll(m & below) << bb;
            tot += (int)__popcll(m & HB) << bb;
        }
        uint regs[8] = {c0, c1, c2, c3, c5, c6, c7, c8};
        float wp = 0.f;
        int k2 = 0;
#pragma unroll
        for (int i = 0; i < 8; ++i) {
            uint ui = regs[i];
            if (ui >= th) {
                ushort w16 = f2h(exp2f((sort2f(ui >> 16) - Mv) * L2E));
                int pos = pre + k2;
                if (pos < MAXL) { sel[qr][pos] = ((uint)w16 << 16) | (ui & 0xFFFFu); wp += h16f(w16); }
                ++k2;
            }
        }
#pragma unroll
        for (int off = 1; off <= 16; off <<= 1) wp += __shfl_xor(wp, off);
        if (s == 0) { wsums[qr] = wp; nks[qr] = (tot < MAXL) ? tot : MAXL; }
    }
    if (s == 0) missflag[qr] = missMy ? 1 : 0;
    __syncthreads();

    // -------- slow rows: bit-exact recompute + full-row exact select --------
    const int kwbase = wave * 256;
    for (int r = 0; r < QROWS; ++r) {
        if (missflag[r]) {                       // block-uniform condition
            __syncthreads();                     // protect Sb1 reuse
#pragma unroll 4
            for (int t = 0; t < 16; ++t) {
                const ushort* Kt = Kb + (size_t)(kwbase + t * 16) * HDIM;
                f16x8 ra0 = *(const f16x8*)(Kt + lr * HDIM + lg * 8);
                f16x8 ra1 = *(const f16x8*)(Kt + lr * HDIM + 32 + lg * 8);
                f32x4 ac2 = {0.f, 0.f, 0.f, 0.f};
                ac2 = __builtin_amdgcn_mfma_f32_16x16x32_f16(ra0, qf0, ac2, 0, 0, 0);
                ac2 = __builtin_amdgcn_mfma_f32_16x16x32_f16(ra1, qf1, ac2, 0, 0, 0);
                if (lr == r) {
                    uint w0 = (uint)f2h(ac2[0]) | ((uint)f2h(ac2[1]) << 16);
                    uint w1 = (uint)f2h(ac2[2]) | ((uint)f2h(ac2[3]) << 16);
                    uint2 pk = {sm2(w0), sm2(w1)};
                    *(uint2*)&Sb1[kwbase + t * 16 + lg * 4] = pk;
                }
            }
            __syncthreads();
            if (wave == (r >> 1)) {              // wave-uniform
                const int h = r & 1;
                const float Mvr = __shfl(Mv, h * 32);
                const uint lor = (uint)__shfl((int)lo, h * 32);
                uint ft = full_thr(Sb1, lane, lor);
                uint thv = ft << 16;
                int cs = recount(Sb1, lane, thv);
                ull below64 = (1ull << lane) - 1ull;
                int preS = 0, totS = 0;
#pragma unroll
                for (int bb = 0; bb < 6; ++bb) {
                    ull m = __ballot((cs >> bb) & 1);
                    preS += (int)__popcll(m & below64) << bb;
                    totS += (int)__popcll(m) << bb;
                }
                float wr = extract_big(Sb1, lane, thv, Mvr, preS, &sel[r][0]);
                if (lane == 0) { wsums[r] = wr; nks[r] = (totS < MAXL) ? totS : MAXL; }
            }
        }
    }
    __syncthreads();

    // -------- sparse PV: half = row, 32 lanes x half2 dims, 8-deep unroll ---
    const __half2* V2 = reinterpret_cast<const __half2*>(vh + (size_t)bh * NSEQ * HDIM);
    const int dp = lane & 31;
    const int nkMy = nks[qr];
    const float wsMy = wsums[qr];
    const uint* selp = &sel[qr][0];

    float ox = 0.f, oy = 0.f;
    int j = 0;
    for (; j + 8 <= nkMy; j += 8) {
        uint e[8];
        *(uint4*)&e[0] = *(const uint4*)(selp + j);
        *(uint4*)&e[4] = *(const uint4*)(selp + j + 4);
        float2 vv[8];
        float ww[8];
#pragma unroll
        for (int i2 = 0; i2 < 8; ++i2) {
            int idx = (int)(e[i2] & 0xFFFFu);
            ww[i2] = h16f((ushort)(e[i2] >> 16));
            vv[i2] = __half22float2(V2[(size_t)idx * 32 + dp]);
        }
#pragma unroll
        for (int i2 = 0; i2 < 8; ++i2) { ox += ww[i2] * vv[i2].x; oy += ww[i2] * vv[i2].y; }
    }
    for (; j < nkMy; ++j) {
        uint e = selp[j];
        int idx = (int)(e & 0xFFFFu);
        float w = h16f((ushort)(e >> 16));
        float2 v0 = __half22float2(V2[(size_t)idx * 32 + dp]);
        ox += w * v0.x; oy += w * v0.y;
    }

    const float inv = 1.f / wsMy;
    uint opk = (uint)f2h(ox * inv) | ((uint)f2h(oy * inv) << 16);
    *(uint*)(ao + ((size_t)(b * NSEQ) + q0 + qr) * DMODEL + hh * HDIM + dp * 2) = opk;
}

// ---------------------------------------------------------------------------
// LN: out = LN(fc_raw + resid) * g + b ; 4 waves/block, 1 row/wave
// ---------------------------------------------------------------------------
__global__ __launch_bounds__(256) void ln_kernel(
    const float* __restrict__ fcr, const float* __restrict__ resid,
    const float* __restrict__ g, const float* __restrict__ bta, float* __restrict__ out)
{
    const int row = blockIdx.x * 4 + (threadIdx.x >> 6);
    const int lane = threadIdx.x & 63;
    const size_t base = (size_t)row * DMODEL + lane * 8;
    float4 xa = *(const float4*)(fcr + base);
    float4 xb = *(const float4*)(fcr + base + 4);
    float4 ra = *(const float4*)(resid + base);
    float4 rb = *(const float4*)(resid + base + 4);
    xa.x += ra.x; xa.y += ra.y; xa.z += ra.z; xa.w += ra.w;
    xb.x += rb.x; xb.y += rb.y; xb.z += rb.z; xb.w += rb.w;
    float sum = xa.x + xa.y + xa.z + xa.w + xb.x + xb.y + xb.z + xb.w;
    float sq = xa.x * xa.x + xa.y * xa.y + xa.z * xa.z + xa.w * xa.w
             + xb.x * xb.x + xb.y * xb.y + xb.z * xb.z + xb.w * xb.w;
#pragma unroll
    for (int off = 32; off >= 1; off >>= 1) {
        sum += __shfl_xor(sum, off);
        sq += __shfl_xor(sq, off);
    }
    float mean = sum * (1.f / 512.f);
    float var = sq * (1.f / 512.f) - mean * mean;
    float rstd = rsqrtf(var + 1e-6f);
    float4 ga = *(const float4*)(g + lane * 8);
    float4 gb = *(const float4*)(g + lane * 8 + 4);
    float4 ba = *(const float4*)(bta + lane * 8);
    float4 bb = *(const float4*)(bta + lane * 8 + 4);
    float4 oa, ob;
    oa.x = (xa.x - mean) * rstd * ga.x + ba.x;
    oa.y = (xa.y - mean) * rstd * ga.y + ba.y;
    oa.z = (xa.z - mean) * rstd * ga.z + ba.z;
    oa.w = (xa.w - mean) * rstd * ga.w + ba.w;
    ob.x = (xb.x - mean) * rstd * gb.x + bb.x;
    ob.y = (xb.y - mean) * rstd * gb.y + bb.y;
    ob.z = (xb.z - mean) * rstd * gb.z + bb.z;
    ob.w = (xb.w - mean) * rstd * gb.w + bb.w;
    *(float4*)(out + base) = oa;
    *(float4*)(out + base + 4) = ob;
}

extern "C" void kernel_launch(void* const* d_in, const int* in_sizes, int n_in,
                              void* d_out, int out_size, void* d_ws, size_t ws_size,
                              hipStream_t stream)
{
    (void)in_sizes; (void)n_in; (void)out_size; (void)ws_size;

    const float* q   = (const float*)d_in[0];
    const float* k   = (const float*)d_in[1];
    const float* v   = (const float*)d_in[2];
    const float* Wq  = (const float*)d_in[3];
    const float* Wk  = (const float*)d_in[4];
    const float* Wv  = (const float*)d_in[5];
    const float* Wfc = (const float*)d_in[6];
    const float* g   = (const float*)d_in[7];
    const float* b   = (const float*)d_in[8];
    float* out = (float*)d_out;

    const size_t SZ = (size_t)BATCH * NSEQ * DMODEL;      // 4,194,304
    const size_t WSZ = (size_t)DMODEL * DMODEL;           // 262,144
    ushort* w16 = (ushort*)d_ws;
    ushort* q16 = w16;
    ushort* k16 = w16 + SZ;
    ushort* v16 = w16 + 2 * SZ;
    ushort* Wt  = w16 + 3 * SZ;                           // 4 matrices
    ushort* qh  = Wt + 4 * WSZ;
    ushort* kh  = qh + SZ;
    ushort* vh  = kh + SZ;
    ushort* ao  = vh + SZ;
    float* fc_raw = (float*)d_ws;   // overlays q16+k16 (dead by fc time)

    cvtA_kernel<<<dim3(2048, 3), 256, 0, stream>>>(q, k, v, q16, k16, v16);
    cvtW_kernel<<<dim3(64, 4), 256, 0, stream>>>(Wq, Wk, Wv, Wfc, Wt);
    hgemm_kernel<0><<<dim3(128, 3), 256, 0, stream>>>(q16, k16, v16, Wt, qh, kh, vh, nullptr);
    attn_kernel<<<dim3(NSEQ / QROWS, BATCH * NHEAD), 512, 0, stream>>>(qh, kh, vh, ao);
    hgemm_kernel<1><<<dim3(128, 1), 256, 0, stream>>>(ao, nullptr, nullptr, Wt, nullptr, nullptr, nullptr, fc_raw);
    ln_kernel<<<(BATCH * NSEQ) / 4, 256, 0, stream>>>(fc_raw, q, g, b, out);
}